// Round 4
// baseline (1672.946 us; speedup 1.0000x reference)
//
#include <hip/hip_runtime.h>
#include <cstdint>
#include <cstddef>

typedef _Float16 h2 __attribute__((ext_vector_type(2)));

__device__ __forceinline__ float sigf(float x) { return 1.0f / (1.0f + __expf(-x)); }
__device__ __forceinline__ float tanhfast(float x) {
  float e = __expf(-2.0f * fabsf(x));
  float t = (1.0f - e) / (1.0f + e);
  return copysignf(t, x);
}
__device__ __forceinline__ h2 cvt2(float a, float b) {
  h2 r; r.x = (_Float16)a; r.y = (_Float16)b; return r;
}
__device__ __forceinline__ h2 bch2(unsigned int u) { return __builtin_bit_cast(h2, u); }

__device__ __forceinline__ float fdot2f(h2 a, h2 b, float c) {
#if __has_builtin(__builtin_amdgcn_fdot2)
  return __builtin_amdgcn_fdot2(a, b, c, false);
#else
  return fmaf((float)a.x, (float)b.x, fmaf((float)a.y, (float)b.y, c));
#endif
}

// ---------------- part encoder ----------------
__global__ void part_encoder(const float* __restrict__ parts, const float* __restrict__ Wpe1,
                             const float* __restrict__ bpe1, const float* __restrict__ Wpe2,
                             const float* __restrict__ bpe2, const float* __restrict__ pos,
                             float* __restrict__ x) {
  __shared__ float prow[16];
  __shared__ float pe1[128];
  int row = blockIdx.x;
  int s = row & 255;
  int tid = threadIdx.x;  // 128
  if (tid < 16) prow[tid] = parts[row * 16 + tid];
  __syncthreads();
  float a = bpe1[tid];
#pragma unroll
  for (int k = 0; k < 16; ++k) a = fmaf(prow[k], Wpe1[tid * 16 + k], a);
  pe1[tid] = fmaxf(a, 0.0f);
  __syncthreads();
  float a2 = bpe2[tid];
  for (int k = 0; k < 128; ++k) a2 = fmaf(pe1[k], Wpe2[tid * 128 + k], a2);
  x[(size_t)row * 256 + tid] = a2;
  if (tid < 64) {
    x[(size_t)row * 256 + 128 + tid] = pos[s * 64 + tid];
    x[(size_t)row * 256 + 192 + tid] = 0.0f;
  }
}

// ---------------- generic f32 GEMM ----------------
template <int ACT>
__global__ __launch_bounds__(256) void gemm_f32(
    const float* __restrict__ A, const float* __restrict__ Wt,
    const float* __restrict__ bias1, const float* __restrict__ bias2,
    float* __restrict__ C, int N, int K) {
  __shared__ float As[16][68];
  __shared__ float Ws[16][68];
  int tid = threadIdx.x;
  int tx = tid & 15, ty = tid >> 4;
  int m0 = blockIdx.y * 64, n0 = blockIdx.x * 64;
  int mm = tid >> 2, c4 = (tid & 3) * 4;
  float acc[4][4] = {};
  for (int k0 = 0; k0 < K; k0 += 16) {
    float4 av = *(const float4*)&A[(size_t)(m0 + mm) * K + k0 + c4];
    float4 wv = *(const float4*)&Wt[(size_t)(n0 + mm) * K + k0 + c4];
    As[c4 + 0][mm] = av.x; As[c4 + 1][mm] = av.y; As[c4 + 2][mm] = av.z; As[c4 + 3][mm] = av.w;
    Ws[c4 + 0][mm] = wv.x; Ws[c4 + 1][mm] = wv.y; Ws[c4 + 2][mm] = wv.z; Ws[c4 + 3][mm] = wv.w;
    __syncthreads();
#pragma unroll
    for (int kk = 0; kk < 16; ++kk) {
      float4 a = *(const float4*)&As[kk][ty * 4];
      float4 w = *(const float4*)&Ws[kk][tx * 4];
      float aa[4] = {a.x, a.y, a.z, a.w};
      float ww[4] = {w.x, w.y, w.z, w.w};
#pragma unroll
      for (int i = 0; i < 4; ++i)
#pragma unroll
        for (int j = 0; j < 4; ++j) acc[i][j] = fmaf(aa[i], ww[j], acc[i][j]);
    }
    __syncthreads();
  }
#pragma unroll
  for (int i = 0; i < 4; ++i) {
    int m = m0 + ty * 4 + i;
    float4 o4;
    float* po = (float*)&o4;
#pragma unroll
    for (int j = 0; j < 4; ++j) {
      int n = n0 + tx * 4 + j;
      float v = acc[i][j] + bias1[n] + (bias2 ? bias2[n] : 0.0f);
      if (ACT == 1) v = fmaxf(v, 0.0f);
      po[j] = v;
    }
    *(float4*)&C[(size_t)m * N + n0 + tx * 4] = o4;
  }
}

// ---------------- attention ----------------
__global__ void attn_kernel(const float* __restrict__ qkv, float* __restrict__ attout) {
  extern __shared__ float sm[];
  float* kl = sm;
  float* ql = sm + 256 * 33;
  float* sc = sm + 256 * 33 + 32 * 33;
  int qt = blockIdx.x, h = blockIdx.y, b = blockIdx.z;
  int tid = threadIdx.x;  // 256
  {
    int j = tid;
    const float* src = qkv + (size_t)(b * 256 + j) * 768 + 256 + h * 32;
#pragma unroll
    for (int d = 0; d < 32; d += 4) {
      float4 v = *(const float4*)(src + d);
      kl[j * 33 + d] = v.x; kl[j * 33 + d + 1] = v.y; kl[j * 33 + d + 2] = v.z; kl[j * 33 + d + 3] = v.w;
    }
  }
  {
    int i = tid >> 3, d4 = (tid & 7) * 4;
    const float* src = qkv + (size_t)(b * 256 + qt * 32 + i) * 768 + h * 32;
    float4 v = *(const float4*)(src + d4);
    ql[i * 33 + d4] = v.x; ql[i * 33 + d4 + 1] = v.y; ql[i * 33 + d4 + 2] = v.z; ql[i * 33 + d4 + 3] = v.w;
  }
  __syncthreads();
  int i = tid >> 3, c = tid & 7;
  const float scale = 0.17677669529663687f;
  float sv[32];
  float mx = -1e30f;
  for (int jj = 0; jj < 32; ++jj) {
    int j = jj * 8 + c;
    float s = 0.0f;
#pragma unroll
    for (int d = 0; d < 32; ++d) s = fmaf(ql[i * 33 + d], kl[j * 33 + d], s);
    s *= scale;
    sv[jj] = s;
    mx = fmaxf(mx, s);
  }
  mx = fmaxf(mx, __shfl_xor(mx, 1));
  mx = fmaxf(mx, __shfl_xor(mx, 2));
  mx = fmaxf(mx, __shfl_xor(mx, 4));
  float sum = 0.0f;
  for (int jj = 0; jj < 32; ++jj) {
    float p = __expf(sv[jj] - mx);
    sc[i * 257 + jj * 8 + c] = p;
    sum += p;
  }
  sum += __shfl_xor(sum, 1);
  sum += __shfl_xor(sum, 2);
  sum += __shfl_xor(sum, 4);
  float inv = 1.0f / sum;
  __syncthreads();
  float a0 = 0, a1 = 0, a2 = 0, a3 = 0;
  int d0 = c * 4;
  const float* vbase = qkv + 512 + h * 32 + d0;
  for (int j = 0; j < 256; ++j) {
    float p = sc[i * 257 + j];
    float4 v = *(const float4*)(vbase + (size_t)(b * 256 + j) * 768);
    a0 = fmaf(p, v.x, a0); a1 = fmaf(p, v.y, a1); a2 = fmaf(p, v.z, a2); a3 = fmaf(p, v.w, a3);
  }
  int orow = b * 256 + qt * 32 + i;
  float4 o4 = {a0 * inv, a1 * inv, a2 * inv, a3 * inv};
  *(float4*)&attout[(size_t)orow * 256 + h * 32 + d0] = o4;
}

// ---------------- LayerNorm(x + o) ----------------
__global__ void ln_residual(float* __restrict__ x, const float* __restrict__ o,
                            const float* __restrict__ g, const float* __restrict__ bt) {
  int row = blockIdx.x, tid = threadIdx.x;  // 256
  float e = x[(size_t)row * 256 + tid] + o[(size_t)row * 256 + tid];
  float s = e, q = e * e;
#pragma unroll
  for (int off = 32; off >= 1; off >>= 1) {
    s += __shfl_xor(s, off);
    q += __shfl_xor(q, off);
  }
  __shared__ float ps[4], pq[4];
  int wid = tid >> 6, lane = tid & 63;
  if (lane == 0) { ps[wid] = s; pq[wid] = q; }
  __syncthreads();
  float St = ps[0] + ps[1] + ps[2] + ps[3];
  float Qt = pq[0] + pq[1] + pq[2] + pq[3];
  float mean = St * (1.0f / 256.0f);
  float var = Qt * (1.0f / 256.0f) - mean * mean;
  float y = (e - mean) * rsqrtf(var + 1e-5f) * g[tid] + bt[tid];
  x[(size_t)row * 256 + tid] = y;
}

// ---------------- gather dec_in ----------------
__global__ void gather_dec_in(const float* __restrict__ enc, const int* __restrict__ ts,
                              float* __restrict__ dec_in) {
  int bx = blockIdx.x;
  int t = bx >> 3, b = bx & 7;
  int tid = threadIdx.x;  // 64
  float4 v = {0.0f, 0.0f, 0.0f, 0.0f};
  if (t > 0) {
    int sidx = ts[b * 256 + t - 1];
    v = *(const float4*)&enc[((size_t)(b * 256 + sidx)) * 256 + tid * 4];
  }
  *(float4*)&dec_in[(size_t)bx * 256 + tid * 4] = v;
}

// ---------------- LSTM scan: 1 block/batch, 1024 threads ----------------
// Thread T = 4*unit + cg owns ALL FOUR gate rows {u, u+256, u+512, u+768} of
// hidden unit u over column slice [64*cg, 64*cg+64). Weights: 4x64 f16 =
// 128 h2 VGPRs (no spill; arch cap is 256). Quad (lanes 4u..4u+3) reduces
// partial dots via 2x shfl_xor (VALU DPP, no LDS); c/h computed redundantly
// in all 4 lanes -> zero LDS gate exchange, ONE barrier per step.
// h broadcast via LDS double-buffer; chunk order rotated by (s+2*cg)&7 so the
// 4 lanes of a quad read 4 distinct bank-quads (conflict-free).
__global__ __attribute__((amdgpu_flat_work_group_size(1024, 1024), amdgpu_waves_per_eu(4, 4)))
void lstm_scan(const float* __restrict__ Xw, const float* __restrict__ Whh,
               float* __restrict__ dec_out) {
  __shared__ _Float16 hbuf[2][256];
  int b = blockIdx.x;
  int T = threadIdx.x;       // 0..1023
  int u = T >> 2;            // hidden unit 0..255
  int cg = T & 3;            // column slice

  h2 w0[32], w1[32], w2[32], w3[32];   // gates i,f,g,o
  {
    const float* base = Whh + (size_t)u * 256;
#pragma unroll
    for (int s = 0; s < 8; ++s) {
      int lc = (s + 2 * cg) & 7;
      int col0 = 64 * cg + 8 * lc;
#pragma unroll
      for (int k = 0; k < 4; ++k) {
        const float4* src = (const float4*)(base + (size_t)k * 65536 + col0);
        float4 v0 = src[0], v1 = src[1];
        h2 p0 = cvt2(v0.x, v0.y), p1 = cvt2(v0.z, v0.w);
        h2 p2 = cvt2(v1.x, v1.y), p3 = cvt2(v1.z, v1.w);
        if (k == 0) { w0[4*s] = p0; w0[4*s+1] = p1; w0[4*s+2] = p2; w0[4*s+3] = p3; }
        else if (k == 1) { w1[4*s] = p0; w1[4*s+1] = p1; w1[4*s+2] = p2; w1[4*s+3] = p3; }
        else if (k == 2) { w2[4*s] = p0; w2[4*s+1] = p1; w2[4*s+2] = p2; w2[4*s+3] = p3; }
        else { w3[4*s] = p0; w3[4*s+1] = p1; w3[4*s+2] = p2; w3[4*s+3] = p3; }
      }
    }
  }
  if (T < 256) hbuf[0][T] = (_Float16)0.0f;
  float c = 0.0f;
  float xnext = Xw[(size_t)(0 * 8 + b) * 1024 + 256 * cg + u];
  __syncthreads();

  for (int t = 0; t < 256; ++t) {
    float xcur = xnext;
    if (t < 255) xnext = Xw[(size_t)((t + 1) * 8 + b) * 1024 + 256 * cg + u];
    const uint4* hb = (const uint4*)hbuf[t & 1];
    float a0 = 0.0f, a1 = 0.0f, a2 = 0.0f, a3 = 0.0f;
#pragma unroll
    for (int s = 0; s < 8; ++s) {
      int lc = (s + 2 * cg) & 7;
      uint4 hv = hb[8 * cg + lc];
      h2 hx = bch2(hv.x), hy = bch2(hv.y), hz = bch2(hv.z), hw = bch2(hv.w);
      a0 = fdot2f(w0[4*s], hx, a0); a0 = fdot2f(w0[4*s+1], hy, a0);
      a0 = fdot2f(w0[4*s+2], hz, a0); a0 = fdot2f(w0[4*s+3], hw, a0);
      a1 = fdot2f(w1[4*s], hx, a1); a1 = fdot2f(w1[4*s+1], hy, a1);
      a1 = fdot2f(w1[4*s+2], hz, a1); a1 = fdot2f(w1[4*s+3], hw, a1);
      a2 = fdot2f(w2[4*s], hx, a2); a2 = fdot2f(w2[4*s+1], hy, a2);
      a2 = fdot2f(w2[4*s+2], hz, a2); a2 = fdot2f(w2[4*s+3], hw, a2);
      a3 = fdot2f(w3[4*s], hx, a3); a3 = fdot2f(w3[4*s+1], hy, a3);
      a3 = fdot2f(w3[4*s+2], hz, a3); a3 = fdot2f(w3[4*s+3], hw, a3);
    }
    // each lane adds Xw for its own gate (added exactly once per gate)
    a0 += (cg == 0) ? xcur : 0.0f;
    a1 += (cg == 1) ? xcur : 0.0f;
    a2 += (cg == 2) ? xcur : 0.0f;
    a3 += (cg == 3) ? xcur : 0.0f;
    // quad butterfly: all 4 lanes get all 4 full gate sums
    a0 += __shfl_xor(a0, 1); a1 += __shfl_xor(a1, 1);
    a2 += __shfl_xor(a2, 1); a3 += __shfl_xor(a3, 1);
    a0 += __shfl_xor(a0, 2); a1 += __shfl_xor(a1, 2);
    a2 += __shfl_xor(a2, 2); a3 += __shfl_xor(a3, 2);
    // redundant c/h update in all 4 lanes (no exchange needed)
    c = sigf(a1) * c + sigf(a0) * tanhfast(a2);
    float hv_ = sigf(a3) * tanhfast(c);
    if (cg == 0) {
      hbuf[(t + 1) & 1][u] = (_Float16)hv_;
      dec_out[((size_t)(b * 256 + t)) * 256 + u] = hv_;
    }
    __syncthreads();
  }
}

// ---------------- pen transpose ----------------
__global__ void transpose_pen(const float* __restrict__ pen, float* __restrict__ penT) {
  int bx = blockIdx.x;
  int b = bx >> 8, h = bx & 255;
  int i = threadIdx.x;  // 256
  penT[(size_t)bx * 256 + i] = pen[((size_t)(b * 256 + i)) * 256 + h];
}

// ---------------- pointer logits ----------------
__global__ void pointer_kernel(const float* __restrict__ pd, const float* __restrict__ penT,
                               const float* __restrict__ vptr, float* __restrict__ out) {
  __shared__ float pdr[256];
  __shared__ float vl[256];
  int bx = blockIdx.x;
  int b = bx >> 8;
  int tid = threadIdx.x;  // 256
  pdr[tid] = pd[(size_t)bx * 256 + tid];
  vl[tid] = vptr[tid];
  __syncthreads();
  const float* pT = penT + (size_t)b * 256 * 256;
  float acc = 0.0f;
  for (int h = 0; h < 256; ++h) {
    acc = fmaf(vl[h], tanhfast(pdr[h] + pT[(size_t)h * 256 + tid]), acc);
  }
  out[(size_t)bx * 256 + tid] = acc;
}

extern "C" void kernel_launch(void* const* d_in, const int* in_sizes, int n_in,
                              void* d_out, int out_size, void* d_ws, size_t ws_size,
                              hipStream_t stream) {
  const float* parts = (const float*)d_in[0];
  const int* ts = (const int*)d_in[1];
  const float* Wpe1 = (const float*)d_in[2];
  const float* bpe1 = (const float*)d_in[3];
  const float* Wpe2 = (const float*)d_in[4];
  const float* bpe2 = (const float*)d_in[5];
  const float* pos = (const float*)d_in[6];
  const float* Wqkv = (const float*)d_in[7];
  const float* bqkv = (const float*)d_in[8];
  const float* Wo = (const float*)d_in[9];
  const float* bo = (const float*)d_in[10];
  const float* ln1g = (const float*)d_in[11];
  const float* ln1b = (const float*)d_in[12];
  const float* W1f = (const float*)d_in[13];
  const float* b1f = (const float*)d_in[14];
  const float* W2f = (const float*)d_in[15];
  const float* b2f = (const float*)d_in[16];
  const float* ln2g = (const float*)d_in[17];
  const float* ln2b = (const float*)d_in[18];
  const float* Wih = (const float*)d_in[19];
  const float* Whh = (const float*)d_in[20];
  const float* bih = (const float*)d_in[21];
  const float* bhh = (const float*)d_in[22];
  const float* Wp = (const float*)d_in[23];
  const float* bp = (const float*)d_in[24];
  const float* vptr = (const float*)d_in[25];
  float* out = (float*)d_out;

  float* W = (float*)d_ws;
  float* xbuf = W;                    // [2048,256]
  float* qkvb = W + 524288;           // [2048,768]
  float* attb = W + 2097152;          // [2048,256]
  float* obuf = W + 2621440;          // [2048,256]
  float* ffb  = W + 3145728;          // [2048,512]
  float* dec_in = obuf;
  float* Xw = qkvb;                   // [2048,1024]
  float* dec_out = ffb;
  float* pdb  = W + 3670016;          // [2048,256]
  float* penb = W + 4194304;          // [2048,256]
  float* penTb = W + 4718592;         // [2048,256]

  const int attnLDS = (256 * 33 + 32 * 33 + 32 * 257) * 4;  // 70912 B
  hipFuncSetAttribute((const void*)attn_kernel, hipFuncAttributeMaxDynamicSharedMemorySize, attnLDS);

  part_encoder<<<2048, 128, 0, stream>>>(parts, Wpe1, bpe1, Wpe2, bpe2, pos, xbuf);
  for (int l = 0; l < 3; ++l) {
    gemm_f32<0><<<dim3(12, 32), 256, 0, stream>>>(xbuf, Wqkv + (size_t)l * 768 * 256,
                                                  bqkv + l * 768, nullptr, qkvb, 768, 256);
    attn_kernel<<<dim3(8, 8, 8), 256, attnLDS, stream>>>(qkvb, attb);
    gemm_f32<0><<<dim3(4, 32), 256, 0, stream>>>(attb, Wo + (size_t)l * 65536,
                                                 bo + l * 256, nullptr, obuf, 256, 256);
    ln_residual<<<2048, 256, 0, stream>>>(xbuf, obuf, ln1g + l * 256, ln1b + l * 256);
    gemm_f32<1><<<dim3(8, 32), 256, 0, stream>>>(xbuf, W1f + (size_t)l * 512 * 256,
                                                 b1f + l * 512, nullptr, ffb, 512, 256);
    gemm_f32<0><<<dim3(4, 32), 256, 0, stream>>>(ffb, W2f + (size_t)l * 256 * 512,
                                                 b2f + l * 256, nullptr, obuf, 256, 512);
    ln_residual<<<2048, 256, 0, stream>>>(xbuf, obuf, ln2g + l * 256, ln2b + l * 256);
  }
  gather_dec_in<<<2048, 64, 0, stream>>>(xbuf, ts, dec_in);
  gemm_f32<0><<<dim3(16, 32), 256, 0, stream>>>(dec_in, Wih, bih, bhh, Xw, 1024, 256);
  lstm_scan<<<8, 1024, 0, stream>>>(Xw, Whh, dec_out);
  gemm_f32<0><<<dim3(4, 32), 256, 0, stream>>>(dec_out, Wp, bp, nullptr, pdb, 256, 256);
  gemm_f32<0><<<dim3(4, 32), 256, 0, stream>>>(xbuf, Wp, bp, nullptr, penb, 256, 256);
  transpose_pen<<<2048, 256, 0, stream>>>(penb, penTb);
  pointer_kernel<<<2048, 256, 0, stream>>>(pdb, penTb, vptr, out);
}

// Round 5
// 985.807 us; speedup vs baseline: 1.6970x; 1.6970x over previous
//
#include <hip/hip_runtime.h>
#include <cstdint>
#include <cstddef>

typedef _Float16 h2 __attribute__((ext_vector_type(2)));

__device__ __forceinline__ float sigf(float x) { return 1.0f / (1.0f + __expf(-x)); }
__device__ __forceinline__ float tanhfast(float x) {
  float e = __expf(-2.0f * fabsf(x));
  float t = (1.0f - e) / (1.0f + e);
  return copysignf(t, x);
}
__device__ __forceinline__ h2 cvt2(float a, float b) {
  h2 r; r.x = (_Float16)a; r.y = (_Float16)b; return r;
}
__device__ __forceinline__ h2 bch2(unsigned int u) { return __builtin_bit_cast(h2, u); }
__device__ __forceinline__ unsigned int bcu(h2 v) { return __builtin_bit_cast(unsigned int, v); }

__device__ __forceinline__ float fdot2f(h2 a, h2 b, float c) {
#if __has_builtin(__builtin_amdgcn_fdot2)
  return __builtin_amdgcn_fdot2(a, b, c, false);
#else
  return fmaf((float)a.x, (float)b.x, fmaf((float)a.y, (float)b.y, c));
#endif
}

// ---------------- part encoder ----------------
__global__ void part_encoder(const float* __restrict__ parts, const float* __restrict__ Wpe1,
                             const float* __restrict__ bpe1, const float* __restrict__ Wpe2,
                             const float* __restrict__ bpe2, const float* __restrict__ pos,
                             float* __restrict__ x) {
  __shared__ float prow[16];
  __shared__ float pe1[128];
  int row = blockIdx.x;
  int s = row & 255;
  int tid = threadIdx.x;  // 128
  if (tid < 16) prow[tid] = parts[row * 16 + tid];
  __syncthreads();
  float a = bpe1[tid];
#pragma unroll
  for (int k = 0; k < 16; ++k) a = fmaf(prow[k], Wpe1[tid * 16 + k], a);
  pe1[tid] = fmaxf(a, 0.0f);
  __syncthreads();
  float a2 = bpe2[tid];
  for (int k = 0; k < 128; ++k) a2 = fmaf(pe1[k], Wpe2[tid * 128 + k], a2);
  x[(size_t)row * 256 + tid] = a2;
  if (tid < 64) {
    x[(size_t)row * 256 + 128 + tid] = pos[s * 64 + tid];
    x[(size_t)row * 256 + 192 + tid] = 0.0f;
  }
}

// ---------------- generic f32 GEMM ----------------
template <int ACT>
__global__ __launch_bounds__(256) void gemm_f32(
    const float* __restrict__ A, const float* __restrict__ Wt,
    const float* __restrict__ bias1, const float* __restrict__ bias2,
    float* __restrict__ C, int N, int K) {
  __shared__ float As[16][68];
  __shared__ float Ws[16][68];
  int tid = threadIdx.x;
  int tx = tid & 15, ty = tid >> 4;
  int m0 = blockIdx.y * 64, n0 = blockIdx.x * 64;
  int mm = tid >> 2, c4 = (tid & 3) * 4;
  float acc[4][4] = {};
  for (int k0 = 0; k0 < K; k0 += 16) {
    float4 av = *(const float4*)&A[(size_t)(m0 + mm) * K + k0 + c4];
    float4 wv = *(const float4*)&Wt[(size_t)(n0 + mm) * K + k0 + c4];
    As[c4 + 0][mm] = av.x; As[c4 + 1][mm] = av.y; As[c4 + 2][mm] = av.z; As[c4 + 3][mm] = av.w;
    Ws[c4 + 0][mm] = wv.x; Ws[c4 + 1][mm] = wv.y; Ws[c4 + 2][mm] = wv.z; Ws[c4 + 3][mm] = wv.w;
    __syncthreads();
#pragma unroll
    for (int kk = 0; kk < 16; ++kk) {
      float4 a = *(const float4*)&As[kk][ty * 4];
      float4 w = *(const float4*)&Ws[kk][tx * 4];
      float aa[4] = {a.x, a.y, a.z, a.w};
      float ww[4] = {w.x, w.y, w.z, w.w};
#pragma unroll
      for (int i = 0; i < 4; ++i)
#pragma unroll
        for (int j = 0; j < 4; ++j) acc[i][j] = fmaf(aa[i], ww[j], acc[i][j]);
    }
    __syncthreads();
  }
#pragma unroll
  for (int i = 0; i < 4; ++i) {
    int m = m0 + ty * 4 + i;
    float4 o4;
    float* po = (float*)&o4;
#pragma unroll
    for (int j = 0; j < 4; ++j) {
      int n = n0 + tx * 4 + j;
      float v = acc[i][j] + bias1[n] + (bias2 ? bias2[n] : 0.0f);
      if (ACT == 1) v = fmaxf(v, 0.0f);
      po[j] = v;
    }
    *(float4*)&C[(size_t)m * N + n0 + tx * 4] = o4;
  }
}

// ---------------- attention ----------------
__global__ void attn_kernel(const float* __restrict__ qkv, float* __restrict__ attout) {
  extern __shared__ float sm[];
  float* kl = sm;
  float* ql = sm + 256 * 33;
  float* sc = sm + 256 * 33 + 32 * 33;
  int qt = blockIdx.x, h = blockIdx.y, b = blockIdx.z;
  int tid = threadIdx.x;  // 256
  {
    int j = tid;
    const float* src = qkv + (size_t)(b * 256 + j) * 768 + 256 + h * 32;
#pragma unroll
    for (int d = 0; d < 32; d += 4) {
      float4 v = *(const float4*)(src + d);
      kl[j * 33 + d] = v.x; kl[j * 33 + d + 1] = v.y; kl[j * 33 + d + 2] = v.z; kl[j * 33 + d + 3] = v.w;
    }
  }
  {
    int i = tid >> 3, d4 = (tid & 7) * 4;
    const float* src = qkv + (size_t)(b * 256 + qt * 32 + i) * 768 + h * 32;
    float4 v = *(const float4*)(src + d4);
    ql[i * 33 + d4] = v.x; ql[i * 33 + d4 + 1] = v.y; ql[i * 33 + d4 + 2] = v.z; ql[i * 33 + d4 + 3] = v.w;
  }
  __syncthreads();
  int i = tid >> 3, c = tid & 7;
  const float scale = 0.17677669529663687f;
  float sv[32];
  float mx = -1e30f;
  for (int jj = 0; jj < 32; ++jj) {
    int j = jj * 8 + c;
    float s = 0.0f;
#pragma unroll
    for (int d = 0; d < 32; ++d) s = fmaf(ql[i * 33 + d], kl[j * 33 + d], s);
    s *= scale;
    sv[jj] = s;
    mx = fmaxf(mx, s);
  }
  mx = fmaxf(mx, __shfl_xor(mx, 1));
  mx = fmaxf(mx, __shfl_xor(mx, 2));
  mx = fmaxf(mx, __shfl_xor(mx, 4));
  float sum = 0.0f;
  for (int jj = 0; jj < 32; ++jj) {
    float p = __expf(sv[jj] - mx);
    sc[i * 257 + jj * 8 + c] = p;
    sum += p;
  }
  sum += __shfl_xor(sum, 1);
  sum += __shfl_xor(sum, 2);
  sum += __shfl_xor(sum, 4);
  float inv = 1.0f / sum;
  __syncthreads();
  float a0 = 0, a1 = 0, a2 = 0, a3 = 0;
  int d0 = c * 4;
  const float* vbase = qkv + 512 + h * 32 + d0;
  for (int j = 0; j < 256; ++j) {
    float p = sc[i * 257 + j];
    float4 v = *(const float4*)(vbase + (size_t)(b * 256 + j) * 768);
    a0 = fmaf(p, v.x, a0); a1 = fmaf(p, v.y, a1); a2 = fmaf(p, v.z, a2); a3 = fmaf(p, v.w, a3);
  }
  int orow = b * 256 + qt * 32 + i;
  float4 o4 = {a0 * inv, a1 * inv, a2 * inv, a3 * inv};
  *(float4*)&attout[(size_t)orow * 256 + h * 32 + d0] = o4;
}

// ---------------- LayerNorm(x + o) ----------------
__global__ void ln_residual(float* __restrict__ x, const float* __restrict__ o,
                            const float* __restrict__ g, const float* __restrict__ bt) {
  int row = blockIdx.x, tid = threadIdx.x;  // 256
  float e = x[(size_t)row * 256 + tid] + o[(size_t)row * 256 + tid];
  float s = e, q = e * e;
#pragma unroll
  for (int off = 32; off >= 1; off >>= 1) {
    s += __shfl_xor(s, off);
    q += __shfl_xor(q, off);
  }
  __shared__ float ps[4], pq[4];
  int wid = tid >> 6, lane = tid & 63;
  if (lane == 0) { ps[wid] = s; pq[wid] = q; }
  __syncthreads();
  float St = ps[0] + ps[1] + ps[2] + ps[3];
  float Qt = pq[0] + pq[1] + pq[2] + pq[3];
  float mean = St * (1.0f / 256.0f);
  float var = Qt * (1.0f / 256.0f) - mean * mean;
  float y = (e - mean) * rsqrtf(var + 1e-5f) * g[tid] + bt[tid];
  x[(size_t)row * 256 + tid] = y;
}

// ---------------- gather dec_in ----------------
__global__ void gather_dec_in(const float* __restrict__ enc, const int* __restrict__ ts,
                              float* __restrict__ dec_in) {
  int bx = blockIdx.x;
  int t = bx >> 3, b = bx & 7;
  int tid = threadIdx.x;  // 64
  float4 v = {0.0f, 0.0f, 0.0f, 0.0f};
  if (t > 0) {
    int sidx = ts[b * 256 + t - 1];
    v = *(const float4*)&enc[((size_t)(b * 256 + sidx)) * 256 + tid * 4];
  }
  *(float4*)&dec_in[(size_t)bx * 256 + tid * 4] = v;
}

// ---------------- LSTM scan: 1 block/batch, 512 threads, lane-paired gates ------
// Thread t = 2u+p: unit u in [0,256), p=0 owns rows {u (i), u+512 (g)},
// p=1 owns rows {u+256 (f), u+768 (o)}. Cols 0..191 of both rows in VGPRs
// (2 x 96 h2 = 192 regs); cols 192..255 in LDS wlds[8][1024] uint4 (128 KB).
// c-update: p0 computes sig(i)*tanh(g), shfl_xor(1) to p1 which holds c.
// One barrier per step. waves_per_eu(2,2) forces the 256-VGPR grant (R3 evidence:
// only a hard max on occupancy makes the allocator give >128).
__global__ __attribute__((amdgpu_flat_work_group_size(512, 512), amdgpu_waves_per_eu(2, 2)))
void lstm_scan(const float* __restrict__ Xw, const float* __restrict__ Whh,
               float* __restrict__ dec_out) {
  extern __shared__ char smem[];
  uint4* wlds = (uint4*)smem;                 // [8][1024] uint4 = 128 KB
  h2* hbuf = (h2*)(smem + 131072);            // [2][128] h2
  int b = blockIdx.x;
  int t0 = threadIdx.x;        // 0..511
  int u = t0 >> 1, p = t0 & 1;
  int rA = u + 256 * p;        // i (p0) / f (p1)
  int rB = u + 512 + 256 * p;  // g (p0) / o (p1)

  h2 w0[96], w1[96];
  {
    const float4* sA = (const float4*)(Whh + (size_t)rA * 256);
    const float4* sB = (const float4*)(Whh + (size_t)rB * 256);
#pragma unroll
    for (int k = 0; k < 48; ++k) {
      float4 v = sA[k];
      w0[2 * k] = cvt2(v.x, v.y);
      w0[2 * k + 1] = cvt2(v.z, v.w);
    }
#pragma unroll
    for (int k = 0; k < 48; ++k) {
      float4 v = sB[k];
      w1[2 * k] = cvt2(v.x, v.y);
      w1[2 * k + 1] = cvt2(v.z, v.w);
    }
#pragma unroll
    for (int qc = 0; qc < 8; ++qc) {
      float4 vA0 = sA[48 + 2 * qc], vA1 = sA[48 + 2 * qc + 1];
      float4 vB0 = sB[48 + 2 * qc], vB1 = sB[48 + 2 * qc + 1];
      uint4 uA, uB;
      uA.x = bcu(cvt2(vA0.x, vA0.y)); uA.y = bcu(cvt2(vA0.z, vA0.w));
      uA.z = bcu(cvt2(vA1.x, vA1.y)); uA.w = bcu(cvt2(vA1.z, vA1.w));
      uB.x = bcu(cvt2(vB0.x, vB0.y)); uB.y = bcu(cvt2(vB0.z, vB0.w));
      uB.z = bcu(cvt2(vB1.x, vB1.y)); uB.w = bcu(cvt2(vB1.z, vB1.w));
      wlds[qc * 1024 + rA] = uA;
      wlds[qc * 1024 + 512 + rB - 512 + 0] = uB;  // rB in [512,1024): same array
    }
  }
  if (t0 < 128) ((uint4*)hbuf)[t0 & 63] = make_uint4(0, 0, 0, 0);  // zero buf0 (first 64 uint4)
  float c = 0.0f;
  float xnA = Xw[(size_t)b * 1024 + rA];
  float xnB = Xw[(size_t)b * 1024 + rB];
  __syncthreads();

  for (int t = 0; t < 256; ++t) {
    float xwA = xnA, xwB = xnB;
    if (t < 255) {
      const float* xp = Xw + (size_t)((t + 1) * 8 + b) * 1024;
      xnA = xp[rA]; xnB = xp[rB];
    }
    const uint4* hb = (const uint4*)(hbuf + (size_t)(t & 1) * 128);
    float a0 = 0.0f, a1 = 0.0f;
#pragma unroll
    for (int q = 0; q < 24; ++q) {  // cols 0..191 from registers
      uint4 hv = hb[q];
      h2 hx = bch2(hv.x), hy = bch2(hv.y), hz = bch2(hv.z), hw = bch2(hv.w);
      a0 = fdot2f(w0[4 * q], hx, a0); a0 = fdot2f(w0[4 * q + 1], hy, a0);
      a0 = fdot2f(w0[4 * q + 2], hz, a0); a0 = fdot2f(w0[4 * q + 3], hw, a0);
      a1 = fdot2f(w1[4 * q], hx, a1); a1 = fdot2f(w1[4 * q + 1], hy, a1);
      a1 = fdot2f(w1[4 * q + 2], hz, a1); a1 = fdot2f(w1[4 * q + 3], hw, a1);
    }
#pragma unroll
    for (int qc = 0; qc < 8; ++qc) {  // cols 192..255 from LDS
      uint4 hv = hb[24 + qc];
      h2 hx = bch2(hv.x), hy = bch2(hv.y), hz = bch2(hv.z), hw = bch2(hv.w);
      uint4 uA = wlds[qc * 1024 + rA];
      uint4 uB = wlds[qc * 1024 + rB];
      a0 = fdot2f(bch2(uA.x), hx, a0); a0 = fdot2f(bch2(uA.y), hy, a0);
      a0 = fdot2f(bch2(uA.z), hz, a0); a0 = fdot2f(bch2(uA.w), hw, a0);
      a1 = fdot2f(bch2(uB.x), hx, a1); a1 = fdot2f(bch2(uB.y), hy, a1);
      a1 = fdot2f(bch2(uB.z), hz, a1); a1 = fdot2f(bch2(uB.w), hw, a1);
    }
    a0 += xwA;  // i (p0) / f (p1)
    a1 += xwB;  // g (p0) / o (p1)
    float ev = sigf(a0) * tanhfast(a1);   // p0: sig(i)*tanh(g); p1: unused value
    float ep = __shfl_xor(ev, 1);         // p1 receives p0's term
    if (p == 1) {
      c = sigf(a0) * c + ep;              // sig(f)*c + sig(i)*tanh(g)
      float hv_ = sigf(a1) * tanhfast(c); // sig(o)*tanh(c)
      ((_Float16*)(hbuf + (size_t)((t + 1) & 1) * 128))[u] = (_Float16)hv_;
      dec_out[((size_t)(b * 256 + t)) * 256 + u] = hv_;
    }
    __syncthreads();
  }
}

// ---------------- pen transpose ----------------
__global__ void transpose_pen(const float* __restrict__ pen, float* __restrict__ penT) {
  int bx = blockIdx.x;
  int b = bx >> 8, h = bx & 255;
  int i = threadIdx.x;  // 256
  penT[(size_t)bx * 256 + i] = pen[((size_t)(b * 256 + i)) * 256 + h];
}

// ---------------- pointer logits ----------------
__global__ void pointer_kernel(const float* __restrict__ pd, const float* __restrict__ penT,
                               const float* __restrict__ vptr, float* __restrict__ out) {
  __shared__ float pdr[256];
  __shared__ float vl[256];
  int bx = blockIdx.x;
  int b = bx >> 8;
  int tid = threadIdx.x;  // 256
  pdr[tid] = pd[(size_t)bx * 256 + tid];
  vl[tid] = vptr[tid];
  __syncthreads();
  const float* pT = penT + (size_t)b * 256 * 256;
  float acc = 0.0f;
  for (int h = 0; h < 256; ++h) {
    acc = fmaf(vl[h], tanhfast(pdr[h] + pT[(size_t)h * 256 + tid]), acc);
  }
  out[(size_t)bx * 256 + tid] = acc;
}

extern "C" void kernel_launch(void* const* d_in, const int* in_sizes, int n_in,
                              void* d_out, int out_size, void* d_ws, size_t ws_size,
                              hipStream_t stream) {
  const float* parts = (const float*)d_in[0];
  const int* ts = (const int*)d_in[1];
  const float* Wpe1 = (const float*)d_in[2];
  const float* bpe1 = (const float*)d_in[3];
  const float* Wpe2 = (const float*)d_in[4];
  const float* bpe2 = (const float*)d_in[5];
  const float* pos = (const float*)d_in[6];
  const float* Wqkv = (const float*)d_in[7];
  const float* bqkv = (const float*)d_in[8];
  const float* Wo = (const float*)d_in[9];
  const float* bo = (const float*)d_in[10];
  const float* ln1g = (const float*)d_in[11];
  const float* ln1b = (const float*)d_in[12];
  const float* W1f = (const float*)d_in[13];
  const float* b1f = (const float*)d_in[14];
  const float* W2f = (const float*)d_in[15];
  const float* b2f = (const float*)d_in[16];
  const float* ln2g = (const float*)d_in[17];
  const float* ln2b = (const float*)d_in[18];
  const float* Wih = (const float*)d_in[19];
  const float* Whh = (const float*)d_in[20];
  const float* bih = (const float*)d_in[21];
  const float* bhh = (const float*)d_in[22];
  const float* Wp = (const float*)d_in[23];
  const float* bp = (const float*)d_in[24];
  const float* vptr = (const float*)d_in[25];
  float* out = (float*)d_out;

  float* W = (float*)d_ws;
  float* xbuf = W;                    // [2048,256]
  float* qkvb = W + 524288;           // [2048,768]
  float* attb = W + 2097152;          // [2048,256]
  float* obuf = W + 2621440;          // [2048,256]
  float* ffb  = W + 3145728;          // [2048,512]
  float* dec_in = obuf;
  float* Xw = qkvb;                   // [2048,1024]
  float* dec_out = ffb;
  float* pdb  = W + 3670016;          // [2048,256]
  float* penb = W + 4194304;          // [2048,256]
  float* penTb = W + 4718592;         // [2048,256]

  const int attnLDS = (256 * 33 + 32 * 33 + 32 * 257) * 4;  // 70912 B
  const int scanLDS = 131072 + 1024;                        // 132096 B
  hipFuncSetAttribute((const void*)attn_kernel, hipFuncAttributeMaxDynamicSharedMemorySize, attnLDS);
  hipFuncSetAttribute((const void*)lstm_scan, hipFuncAttributeMaxDynamicSharedMemorySize, scanLDS);

  part_encoder<<<2048, 128, 0, stream>>>(parts, Wpe1, bpe1, Wpe2, bpe2, pos, xbuf);
  for (int l = 0; l < 3; ++l) {
    gemm_f32<0><<<dim3(12, 32), 256, 0, stream>>>(xbuf, Wqkv + (size_t)l * 768 * 256,
                                                  bqkv + l * 768, nullptr, qkvb, 768, 256);
    attn_kernel<<<dim3(8, 8, 8), 256, attnLDS, stream>>>(qkvb, attb);
    gemm_f32<0><<<dim3(4, 32), 256, 0, stream>>>(attb, Wo + (size_t)l * 65536,
                                                 bo + l * 256, nullptr, obuf, 256, 256);
    ln_residual<<<2048, 256, 0, stream>>>(xbuf, obuf, ln1g + l * 256, ln1b + l * 256);
    gemm_f32<1><<<dim3(8, 32), 256, 0, stream>>>(xbuf, W1f + (size_t)l * 512 * 256,
                                                 b1f + l * 512, nullptr, ffb, 512, 256);
    gemm_f32<0><<<dim3(4, 32), 256, 0, stream>>>(ffb, W2f + (size_t)l * 256 * 512,
                                                 b2f + l * 256, nullptr, obuf, 256, 512);
    ln_residual<<<2048, 256, 0, stream>>>(xbuf, obuf, ln2g + l * 256, ln2b + l * 256);
  }
  gather_dec_in<<<2048, 64, 0, stream>>>(xbuf, ts, dec_in);
  gemm_f32<0><<<dim3(16, 32), 256, 0, stream>>>(dec_in, Wih, bih, bhh, Xw, 1024, 256);
  lstm_scan<<<8, 512, scanLDS, stream>>>(Xw, Whh, dec_out);
  gemm_f32<0><<<dim3(4, 32), 256, 0, stream>>>(dec_out, Wp, bp, nullptr, pdb, 256, 256);
  gemm_f32<0><<<dim3(4, 32), 256, 0, stream>>>(xbuf, Wp, bp, nullptr, penb, 256, 256);
  transpose_pen<<<2048, 256, 0, stream>>>(penb, penTb);
  pointer_kernel<<<2048, 256, 0, stream>>>(pdb, penTb, vptr, out);
}

// Round 6
// 863.201 us; speedup vs baseline: 1.9381x; 1.1420x over previous
//
#include <hip/hip_runtime.h>
#include <cstdint>
#include <cstddef>

typedef _Float16 h2 __attribute__((ext_vector_type(2)));
typedef short bf16x8 __attribute__((ext_vector_type(8)));
typedef float f32x4 __attribute__((ext_vector_type(4)));

__device__ __forceinline__ float sigf(float x) { return 1.0f / (1.0f + __expf(-x)); }
__device__ __forceinline__ float tanhfast(float x) {
  float e = __expf(-2.0f * fabsf(x));
  float t = (1.0f - e) / (1.0f + e);
  return copysignf(t, x);
}
__device__ __forceinline__ h2 cvt2(float a, float b) {
  h2 r; r.x = (_Float16)a; r.y = (_Float16)b; return r;
}
__device__ __forceinline__ h2 bch2(unsigned int u) { return __builtin_bit_cast(h2, u); }
__device__ __forceinline__ unsigned int bcu(h2 v) { return __builtin_bit_cast(unsigned int, v); }
__device__ __forceinline__ unsigned short f2bf(float f) {
  unsigned int u = __float_as_uint(f);
  u = (u + 0x7fffu + ((u >> 16) & 1u)) >> 16;
  return (unsigned short)u;
}

__device__ __forceinline__ float fdot2f(h2 a, h2 b, float c) {
#if __has_builtin(__builtin_amdgcn_fdot2)
  return __builtin_amdgcn_fdot2(a, b, c, false);
#else
  return fmaf((float)a.x, (float)b.x, fmaf((float)a.y, (float)b.y, c));
#endif
}

// ---------------- f32 -> bf16 convert (weights, once per call) ----------------
__global__ void convert_bf(const float* __restrict__ src, ushort* __restrict__ dst, int n) {
  int i = blockIdx.x * 256 + threadIdx.x;
  if (i < n) dst[i] = f2bf(src[i]);
}

// ---------------- part encoder: writes f32 x and bf16 xbf ----------------
__global__ void part_encoder(const float* __restrict__ parts, const float* __restrict__ Wpe1,
                             const float* __restrict__ bpe1, const float* __restrict__ Wpe2,
                             const float* __restrict__ bpe2, const float* __restrict__ pos,
                             float* __restrict__ x, ushort* __restrict__ xb) {
  __shared__ float prow[16];
  __shared__ float pe1[128];
  int row = blockIdx.x;
  int s = row & 255;
  int tid = threadIdx.x;  // 128
  if (tid < 16) prow[tid] = parts[row * 16 + tid];
  __syncthreads();
  float a = bpe1[tid];
#pragma unroll
  for (int k = 0; k < 16; ++k) a = fmaf(prow[k], Wpe1[tid * 16 + k], a);
  pe1[tid] = fmaxf(a, 0.0f);
  __syncthreads();
  float a2 = bpe2[tid];
  for (int k = 0; k < 128; ++k) a2 = fmaf(pe1[k], Wpe2[tid * 128 + k], a2);
  x[(size_t)row * 256 + tid] = a2;
  xb[(size_t)row * 256 + tid] = f2bf(a2);
  if (tid < 64) {
    float p = pos[s * 64 + tid];
    x[(size_t)row * 256 + 128 + tid] = p;
    xb[(size_t)row * 256 + 128 + tid] = f2bf(p);
    x[(size_t)row * 256 + 192 + tid] = 0.0f;
    xb[(size_t)row * 256 + 192 + tid] = 0;
  }
}

// ---------------- MFMA bf16 GEMM: C[m,n] = act(A[m,:] . Wt[n,:] + b1 (+b2)) ----
// A [M,K] bf16 row-major, Wt [N,K] bf16 row-major. 256 thr = 4 waves; wave w
// computes rows m0+w*16..+15, cols n0..n0+63 (4x 16x16 mfma tiles).
// Frag layouts (m89-verified): A/B lane l: row/col = l&15, k-octet = l>>4.
// C: col = lane&15, row = (lane>>4)*4 + r.
template <int ACT, int OUTBF>
__global__ __launch_bounds__(256) void gemm_bf16(
    const ushort* __restrict__ A, const ushort* __restrict__ Wt,
    const float* __restrict__ bias1, const float* __restrict__ bias2,
    void* __restrict__ Cout, int N, int K) {
  int wid = threadIdx.x >> 6;
  int lane = threadIdx.x & 63;
  int m0 = blockIdx.y * 64 + wid * 16;
  int n0 = blockIdx.x * 64;
  int r15 = lane & 15;
  int kg = lane >> 4;
  f32x4 acc0 = {0.f, 0.f, 0.f, 0.f}, acc1 = acc0, acc2 = acc0, acc3 = acc0;
  const ushort* arow = A + (size_t)(m0 + r15) * K + kg * 8;
  const ushort* w0 = Wt + (size_t)(n0 + r15) * K + kg * 8;
  const ushort* w1 = w0 + (size_t)16 * K;
  const ushort* w2 = w0 + (size_t)32 * K;
  const ushort* w3 = w0 + (size_t)48 * K;
  for (int k0 = 0; k0 < K; k0 += 32) {
    bf16x8 af = *(const bf16x8*)(arow + k0);
    bf16x8 b0 = *(const bf16x8*)(w0 + k0);
    bf16x8 b1 = *(const bf16x8*)(w1 + k0);
    bf16x8 b2 = *(const bf16x8*)(w2 + k0);
    bf16x8 b3 = *(const bf16x8*)(w3 + k0);
    acc0 = __builtin_amdgcn_mfma_f32_16x16x32_bf16(af, b0, acc0, 0, 0, 0);
    acc1 = __builtin_amdgcn_mfma_f32_16x16x32_bf16(af, b1, acc1, 0, 0, 0);
    acc2 = __builtin_amdgcn_mfma_f32_16x16x32_bf16(af, b2, acc2, 0, 0, 0);
    acc3 = __builtin_amdgcn_mfma_f32_16x16x32_bf16(af, b3, acc3, 0, 0, 0);
  }
#pragma unroll
  for (int nn = 0; nn < 4; ++nn) {
    f32x4 a = (nn == 0) ? acc0 : (nn == 1) ? acc1 : (nn == 2) ? acc2 : acc3;
    int n = n0 + nn * 16 + r15;
    float bsum = bias1[n] + (bias2 ? bias2[n] : 0.0f);
#pragma unroll
    for (int r = 0; r < 4; ++r) {
      int m = m0 + kg * 4 + r;
      float v = a[r] + bsum;
      if (ACT == 1) v = fmaxf(v, 0.0f);
      if (OUTBF == 1)
        ((ushort*)Cout)[(size_t)m * N + n] = f2bf(v);
      else
        ((float*)Cout)[(size_t)m * N + n] = v;
    }
  }
}

// ---------------- attention (f32 in, bf16 out) ----------------
__global__ void attn_kernel(const float* __restrict__ qkv, ushort* __restrict__ attout) {
  extern __shared__ float sm[];
  float* kl = sm;
  float* ql = sm + 256 * 33;
  float* sc = sm + 256 * 33 + 32 * 33;
  int qt = blockIdx.x, h = blockIdx.y, b = blockIdx.z;
  int tid = threadIdx.x;  // 256
  {
    int j = tid;
    const float* src = qkv + (size_t)(b * 256 + j) * 768 + 256 + h * 32;
#pragma unroll
    for (int d = 0; d < 32; d += 4) {
      float4 v = *(const float4*)(src + d);
      kl[j * 33 + d] = v.x; kl[j * 33 + d + 1] = v.y; kl[j * 33 + d + 2] = v.z; kl[j * 33 + d + 3] = v.w;
    }
  }
  {
    int i = tid >> 3, d4 = (tid & 7) * 4;
    const float* src = qkv + (size_t)(b * 256 + qt * 32 + i) * 768 + h * 32;
    float4 v = *(const float4*)(src + d4);
    ql[i * 33 + d4] = v.x; ql[i * 33 + d4 + 1] = v.y; ql[i * 33 + d4 + 2] = v.z; ql[i * 33 + d4 + 3] = v.w;
  }
  __syncthreads();
  int i = tid >> 3, c = tid & 7;
  const float scale = 0.17677669529663687f;
  float sv[32];
  float mx = -1e30f;
  for (int jj = 0; jj < 32; ++jj) {
    int j = jj * 8 + c;
    float s = 0.0f;
#pragma unroll
    for (int d = 0; d < 32; ++d) s = fmaf(ql[i * 33 + d], kl[j * 33 + d], s);
    s *= scale;
    sv[jj] = s;
    mx = fmaxf(mx, s);
  }
  mx = fmaxf(mx, __shfl_xor(mx, 1));
  mx = fmaxf(mx, __shfl_xor(mx, 2));
  mx = fmaxf(mx, __shfl_xor(mx, 4));
  float sum = 0.0f;
  for (int jj = 0; jj < 32; ++jj) {
    float p = __expf(sv[jj] - mx);
    sc[i * 257 + jj * 8 + c] = p;
    sum += p;
  }
  sum += __shfl_xor(sum, 1);
  sum += __shfl_xor(sum, 2);
  sum += __shfl_xor(sum, 4);
  float inv = 1.0f / sum;
  __syncthreads();
  float a0 = 0, a1 = 0, a2 = 0, a3 = 0;
  int d0 = c * 4;
  const float* vbase = qkv + 512 + h * 32 + d0;
  for (int j = 0; j < 256; ++j) {
    float p = sc[i * 257 + j];
    float4 v = *(const float4*)(vbase + (size_t)(b * 256 + j) * 768);
    a0 = fmaf(p, v.x, a0); a1 = fmaf(p, v.y, a1); a2 = fmaf(p, v.z, a2); a3 = fmaf(p, v.w, a3);
  }
  int orow = b * 256 + qt * 32 + i;
  ushort4 o4;
  o4.x = f2bf(a0 * inv); o4.y = f2bf(a1 * inv); o4.z = f2bf(a2 * inv); o4.w = f2bf(a3 * inv);
  *(ushort4*)&attout[(size_t)orow * 256 + h * 32 + d0] = o4;
}

// ---------------- LayerNorm(x + o): writes f32 x and bf16 xbf ----------------
__global__ void ln_residual(float* __restrict__ x, const float* __restrict__ o,
                            const float* __restrict__ g, const float* __restrict__ bt,
                            ushort* __restrict__ xb) {
  int row = blockIdx.x, tid = threadIdx.x;  // 256
  float e = x[(size_t)row * 256 + tid] + o[(size_t)row * 256 + tid];
  float s = e, q = e * e;
#pragma unroll
  for (int off = 32; off >= 1; off >>= 1) {
    s += __shfl_xor(s, off);
    q += __shfl_xor(q, off);
  }
  __shared__ float ps[4], pq[4];
  int wid = tid >> 6, lane = tid & 63;
  if (lane == 0) { ps[wid] = s; pq[wid] = q; }
  __syncthreads();
  float St = ps[0] + ps[1] + ps[2] + ps[3];
  float Qt = pq[0] + pq[1] + pq[2] + pq[3];
  float mean = St * (1.0f / 256.0f);
  float var = Qt * (1.0f / 256.0f) - mean * mean;
  float y = (e - mean) * rsqrtf(var + 1e-5f) * g[tid] + bt[tid];
  x[(size_t)row * 256 + tid] = y;
  xb[(size_t)row * 256 + tid] = f2bf(y);
}

// ---------------- gather dec_in (bf16 -> bf16) ----------------
__global__ void gather_dec_in(const ushort* __restrict__ encb, const int* __restrict__ ts,
                              ushort* __restrict__ dec_in) {
  int bx = blockIdx.x;
  int t = bx >> 3, b = bx & 7;
  int tid = threadIdx.x;  // 64
  ushort4 v = {0, 0, 0, 0};
  if (t > 0) {
    int sidx = ts[b * 256 + t - 1];
    v = *(const ushort4*)&encb[((size_t)(b * 256 + sidx)) * 256 + tid * 4];
  }
  *(ushort4*)&dec_in[(size_t)bx * 256 + tid * 4] = v;
}

// ---------------- LSTM scan: R5 structure, waves_per_eu(1,1) for 256-VGPR grant --
// Thread t = 2u+p: p0 owns rows {u (i), u+512 (g)}, p1 owns {u+256 (f), u+768 (o)}.
// Cols 0..191 in VGPRs (192 regs), cols 192..255 in LDS [8][1024] uint4 (128 KB).
// Grant rule (R1-R5 evidence): vgpr_cap = 256 / min_waves_per_eu -> (1,1) = 256.
// Need 192 weights + ~30 working = 222 <= 256 -> no spill. Per-SIMD file = 512
// regs (m69) so 8 waves still fit at 2 waves/SIMD x 256.
__global__ __attribute__((amdgpu_flat_work_group_size(512, 512), amdgpu_waves_per_eu(1, 1)))
void lstm_scan(const float* __restrict__ Xw, const float* __restrict__ Whh,
               ushort* __restrict__ dec_out) {
  extern __shared__ char smem[];
  uint4* wlds = (uint4*)smem;                 // [8][1024] uint4 = 128 KB
  h2* hbuf = (h2*)(smem + 131072);            // [2][128] h2
  int b = blockIdx.x;
  int t0 = threadIdx.x;        // 0..511
  int u = t0 >> 1, p = t0 & 1;
  int rA = u + 256 * p;        // i (p0) / f (p1)
  int rB = u + 512 + 256 * p;  // g (p0) / o (p1)

  h2 w0[96], w1[96];
  {
    const float4* sA = (const float4*)(Whh + (size_t)rA * 256);
    const float4* sB = (const float4*)(Whh + (size_t)rB * 256);
#pragma unroll
    for (int k = 0; k < 48; ++k) {
      float4 v = sA[k];
      w0[2 * k] = cvt2(v.x, v.y);
      w0[2 * k + 1] = cvt2(v.z, v.w);
    }
#pragma unroll
    for (int k = 0; k < 48; ++k) {
      float4 v = sB[k];
      w1[2 * k] = cvt2(v.x, v.y);
      w1[2 * k + 1] = cvt2(v.z, v.w);
    }
#pragma unroll
    for (int qc = 0; qc < 8; ++qc) {
      float4 vA0 = sA[48 + 2 * qc], vA1 = sA[48 + 2 * qc + 1];
      float4 vB0 = sB[48 + 2 * qc], vB1 = sB[48 + 2 * qc + 1];
      uint4 uA, uB;
      uA.x = bcu(cvt2(vA0.x, vA0.y)); uA.y = bcu(cvt2(vA0.z, vA0.w));
      uA.z = bcu(cvt2(vA1.x, vA1.y)); uA.w = bcu(cvt2(vA1.z, vA1.w));
      uB.x = bcu(cvt2(vB0.x, vB0.y)); uB.y = bcu(cvt2(vB0.z, vB0.w));
      uB.z = bcu(cvt2(vB1.x, vB1.y)); uB.w = bcu(cvt2(vB1.z, vB1.w));
      wlds[qc * 1024 + rA] = uA;
      wlds[qc * 1024 + rB] = uB;
    }
  }
  if (t0 < 128) ((uint4*)hbuf)[t0 & 63] = make_uint4(0, 0, 0, 0);
  float c = 0.0f;
  float xnA = Xw[(size_t)b * 1024 + rA];
  float xnB = Xw[(size_t)b * 1024 + rB];
  __syncthreads();

  for (int t = 0; t < 256; ++t) {
    float xwA = xnA, xwB = xnB;
    if (t < 255) {
      const float* xp = Xw + (size_t)((t + 1) * 8 + b) * 1024;
      xnA = xp[rA]; xnB = xp[rB];
    }
    const uint4* hb = (const uint4*)(hbuf + (size_t)(t & 1) * 128);
    float a0 = 0.0f, a1 = 0.0f;
#pragma unroll
    for (int q = 0; q < 24; ++q) {  // cols 0..191 from registers
      uint4 hv = hb[q];
      h2 hx = bch2(hv.x), hy = bch2(hv.y), hz = bch2(hv.z), hw = bch2(hv.w);
      a0 = fdot2f(w0[4 * q], hx, a0); a0 = fdot2f(w0[4 * q + 1], hy, a0);
      a0 = fdot2f(w0[4 * q + 2], hz, a0); a0 = fdot2f(w0[4 * q + 3], hw, a0);
      a1 = fdot2f(w1[4 * q], hx, a1); a1 = fdot2f(w1[4 * q + 1], hy, a1);
      a1 = fdot2f(w1[4 * q + 2], hz, a1); a1 = fdot2f(w1[4 * q + 3], hw, a1);
    }
#pragma unroll
    for (int qc = 0; qc < 8; ++qc) {  // cols 192..255 from LDS
      uint4 hv = hb[24 + qc];
      h2 hx = bch2(hv.x), hy = bch2(hv.y), hz = bch2(hv.z), hw = bch2(hv.w);
      uint4 uA = wlds[qc * 1024 + rA];
      uint4 uB = wlds[qc * 1024 + rB];
      a0 = fdot2f(bch2(uA.x), hx, a0); a0 = fdot2f(bch2(uA.y), hy, a0);
      a0 = fdot2f(bch2(uA.z), hz, a0); a0 = fdot2f(bch2(uA.w), hw, a0);
      a1 = fdot2f(bch2(uB.x), hx, a1); a1 = fdot2f(bch2(uB.y), hy, a1);
      a1 = fdot2f(bch2(uB.z), hz, a1); a1 = fdot2f(bch2(uB.w), hw, a1);
    }
    a0 += xwA;  // i (p0) / f (p1)
    a1 += xwB;  // g (p0) / o (p1)
    float ev = sigf(a0) * tanhfast(a1);   // p0: sig(i)*tanh(g)
    float ep = __shfl_xor(ev, 1);
    if (p == 1) {
      c = sigf(a0) * c + ep;              // sig(f)*c + sig(i)*tanh(g)
      float hv_ = sigf(a1) * tanhfast(c); // sig(o)*tanh(c)
      ((_Float16*)(hbuf + (size_t)((t + 1) & 1) * 128))[u] = (_Float16)hv_;
      dec_out[((size_t)(b * 256 + t)) * 256 + u] = f2bf(hv_);
    }
    __syncthreads();
  }
}

// ---------------- pen transpose ----------------
__global__ void transpose_pen(const float* __restrict__ pen, float* __restrict__ penT) {
  int bx = blockIdx.x;
  int b = bx >> 8, h = bx & 255;
  int i = threadIdx.x;  // 256
  penT[(size_t)bx * 256 + i] = pen[((size_t)(b * 256 + i)) * 256 + h];
}

// ---------------- pointer logits ----------------
__global__ void pointer_kernel(const float* __restrict__ pd, const float* __restrict__ penT,
                               const float* __restrict__ vptr, float* __restrict__ out) {
  __shared__ float pdr[256];
  __shared__ float vl[256];
  int bx = blockIdx.x;
  int b = bx >> 8;
  int tid = threadIdx.x;  // 256
  pdr[tid] = pd[(size_t)bx * 256 + tid];
  vl[tid] = vptr[tid];
  __syncthreads();
  const float* pT = penT + (size_t)b * 256 * 256;
  float acc = 0.0f;
  for (int h = 0; h < 256; ++h) {
    acc = fmaf(vl[h], tanhfast(pdr[h] + pT[(size_t)h * 256 + tid]), acc);
  }
  out[(size_t)bx * 256 + tid] = acc;
}

extern "C" void kernel_launch(void* const* d_in, const int* in_sizes, int n_in,
                              void* d_out, int out_size, void* d_ws, size_t ws_size,
                              hipStream_t stream) {
  const float* parts = (const float*)d_in[0];
  const int* ts = (const int*)d_in[1];
  const float* Wpe1 = (const float*)d_in[2];
  const float* bpe1 = (const float*)d_in[3];
  const float* Wpe2 = (const float*)d_in[4];
  const float* bpe2 = (const float*)d_in[5];
  const float* pos = (const float*)d_in[6];
  const float* Wqkv = (const float*)d_in[7];
  const float* bqkv = (const float*)d_in[8];
  const float* Wo = (const float*)d_in[9];
  const float* bo = (const float*)d_in[10];
  const float* ln1g = (const float*)d_in[11];
  const float* ln1b = (const float*)d_in[12];
  const float* W1f = (const float*)d_in[13];
  const float* b1f = (const float*)d_in[14];
  const float* W2f = (const float*)d_in[15];
  const float* b2f = (const float*)d_in[16];
  const float* ln2g = (const float*)d_in[17];
  const float* ln2b = (const float*)d_in[18];
  const float* Wih = (const float*)d_in[19];
  const float* Whh = (const float*)d_in[20];
  const float* bih = (const float*)d_in[21];
  const float* bhh = (const float*)d_in[22];
  const float* Wp = (const float*)d_in[23];
  const float* bp = (const float*)d_in[24];
  const float* vptr = (const float*)d_in[25];
  float* out = (float*)d_out;

  // ---- workspace layout (f32-slot units); total 4620288 slots = 18.5 MB ----
  float* W = (float*)d_ws;
  float* xbuf = W;                            // [2048,256] f32, live all
  ushort* xbf = (ushort*)(W + 524288);        // [2048,256] bf16, live all
  float* SCR = W + 786432;                    // 2097152 slots scratch
  float* qkvb = SCR;                          //   encoder: [2048,768] f32
  float* obuf = SCR + 1572864;                //   encoder: [2048,256] f32
  float* Xw = SCR;                            //   decoder: [2048,1024] f32
  float* pdb = SCR;                           //   tail: [2048,256] f32
  float* penb = SCR + 524288;                 //   tail: [2048,256] f32
  float* penTb = SCR + 1048576;               //   tail: [2048,256] f32
  ushort* attbf = (ushort*)(W + 2883584);     // [2048,256] bf16 (encoder)
  ushort* ffbf = (ushort*)(W + 3145728);      // [2048,512] bf16 (encoder)
  ushort* dec_inbf = (ushort*)(W + 3145728);  //   decoder: [2048,256] bf16
  ushort* dec_outbf = (ushort*)(W + 3407872); //   decoder: [2048,256] bf16
  ushort* wqkvbf = (ushort*)(W + 3670016);    // 589824 bf16
  ushort* wobf   = (ushort*)(W + 3964928);    // 196608
  ushort* w1fbf  = (ushort*)(W + 4063232);    // 393216
  ushort* w2fbf  = (ushort*)(W + 4259840);    // 393216
  ushort* wihbf  = (ushort*)(W + 4456448);    // 262144
  ushort* wpbf   = (ushort*)(W + 4587520);    // 65536

  const int attnLDS = (256 * 33 + 32 * 33 + 32 * 257) * 4;  // 70912 B
  const int scanLDS = 131072 + 1024;                        // 132096 B
  hipFuncSetAttribute((const void*)attn_kernel, hipFuncAttributeMaxDynamicSharedMemorySize, attnLDS);
  hipFuncSetAttribute((const void*)lstm_scan, hipFuncAttributeMaxDynamicSharedMemorySize, scanLDS);

  // weight conversions (one-time per call, ~4 MB total)
  convert_bf<<<(589824 + 255) / 256, 256, 0, stream>>>(Wqkv, wqkvbf, 589824);
  convert_bf<<<(196608 + 255) / 256, 256, 0, stream>>>(Wo, wobf, 196608);
  convert_bf<<<(393216 + 255) / 256, 256, 0, stream>>>(W1f, w1fbf, 393216);
  convert_bf<<<(393216 + 255) / 256, 256, 0, stream>>>(W2f, w2fbf, 393216);
  convert_bf<<<(262144 + 255) / 256, 256, 0, stream>>>(Wih, wihbf, 262144);
  convert_bf<<<(65536 + 255) / 256, 256, 0, stream>>>(Wp, wpbf, 65536);

  part_encoder<<<2048, 128, 0, stream>>>(parts, Wpe1, bpe1, Wpe2, bpe2, pos, xbuf, xbf);
  for (int l = 0; l < 3; ++l) {
    gemm_bf16<0, 0><<<dim3(12, 32), 256, 0, stream>>>(xbf, wqkvbf + (size_t)l * 196608,
                                                      bqkv + l * 768, nullptr, qkvb, 768, 256);
    attn_kernel<<<dim3(8, 8, 8), 256, attnLDS, stream>>>(qkvb, attbf);
    gemm_bf16<0, 0><<<dim3(4, 32), 256, 0, stream>>>(attbf, wobf + (size_t)l * 65536,
                                                     bo + l * 256, nullptr, obuf, 256, 256);
    ln_residual<<<2048, 256, 0, stream>>>(xbuf, obuf, ln1g + l * 256, ln1b + l * 256, xbf);
    gemm_bf16<1, 1><<<dim3(8, 32), 256, 0, stream>>>(xbf, w1fbf + (size_t)l * 131072,
                                                     b1f + l * 512, nullptr, ffbf, 512, 256);
    gemm_bf16<0, 0><<<dim3(4, 32), 256, 0, stream>>>(ffbf, w2fbf + (size_t)l * 131072,
                                                     b2f + l * 256, nullptr, obuf, 256, 512);
    ln_residual<<<2048, 256, 0, stream>>>(xbuf, obuf, ln2g + l * 256, ln2b + l * 256, xbf);
  }
  gather_dec_in<<<2048, 64, 0, stream>>>(xbf, ts, dec_inbf);
  gemm_bf16<0, 0><<<dim3(16, 32), 256, 0, stream>>>(dec_inbf, wihbf, bih, bhh, Xw, 1024, 256);
  lstm_scan<<<8, 512, scanLDS, stream>>>(Xw, Whh, dec_outbf);
  gemm_bf16<0, 0><<<dim3(4, 32), 256, 0, stream>>>(dec_outbf, wpbf, bp, nullptr, pdb, 256, 256);
  gemm_bf16<0, 0><<<dim3(4, 32), 256, 0, stream>>>(xbf, wpbf, bp, nullptr, penb, 256, 256);
  transpose_pen<<<2048, 256, 0, stream>>>(penb, penTb);
  pointer_kernel<<<2048, 256, 0, stream>>>(pdb, penTb, vptr, out);
}